// Round 6
// baseline (123.219 us; speedup 1.0000x reference)
//
#include <hip/hip_runtime.h>
#include <utility>

#define FIELD 39
#define TILE  13      // 3 tiles of 13
#define DIM   16
#define BATCH 8192
#define EPAD  42      // 39 real + 3 zero pad (padded-row FMAs may index up to 41)

// ---- compile-time weight layout: block-padded, every row 16B-aligned ----
constexpr int widx(int i, int j) { return i*(FIELD-1) - i*(i-1)/2 + (j-i-1); }
constexpr int ceil4(int x) { return (x+3) & ~3; }
constexpr int OFF_ROW  = 16;                 // off-diag row padded 13 -> 16
constexpr int OFF_TILE = TILE * OFF_ROW;     // 208
constexpr int diag_rowstart(int II) {        // triangular rows, padded to x4
    int s = 0; for (int m = 0; m < II; ++m) s += ceil4(TILE-1-m); return s;
}
constexpr int DIAG_TILE = diag_rowstart(TILE);          // 96
constexpr int off_base(int t) { return t * OFF_TILE; }  // t: 0=(0,1) 1=(0,2) 2=(1,2)
constexpr int diag_base(int A) { return 3*OFF_TILE + A*DIAG_TILE; }
constexpr int WTOT = 3*OFF_TILE + 3*DIAG_TILE;          // 912 floats = 3.6 KB

struct WMap { int v[WTOT]; };
constexpr WMap make_map() {
    WMap m{};
    for (int i = 0; i < WTOT; ++i) m.v[i] = -1;          // -1 -> 0.0f pad
    const int AB[3][2] = {{0,1},{0,2},{1,2}};
    for (int t = 0; t < 3; ++t)
        for (int II = 0; II < TILE; ++II)
            for (int c = 0; c < TILE; ++c)
                m.v[off_base(t) + II*OFF_ROW + c] = widx(AB[t][0]*TILE+II, AB[t][1]*TILE+c);
    for (int A = 0; A < 3; ++A)
        for (int II = 0; II < TILE-1; ++II)
            for (int k = 0; k < TILE-1-II; ++k)
                m.v[diag_base(A) + diag_rowstart(II) + k] = widx(A*TILE+II, A*TILE+II+1+k);
    return m;
}
__device__ constexpr WMap g_map = make_map();

// ---- compute machinery: every index a literal after instantiation ----
__device__ __forceinline__ float4 ld4(const float* lds, int ofs) {
    return *reinterpret_cast<const float4*>(lds + ofs);   // ds_read_b128, imm offset
}
template <int EB>
__device__ __forceinline__ float fma4(float4 w, const float (&e)[EPAD], float s) {
    s = fmaf(w.x, e[EB+0], s); s = fmaf(w.y, e[EB+1], s);
    s = fmaf(w.z, e[EB+2], s); s = fmaf(w.w, e[EB+3], s);
    return s;
}
template <int RBASE, int EBASE, size_t... Qs>
__device__ __forceinline__ float row_q(const float* lds, const float (&e)[EPAD],
                                       std::index_sequence<Qs...>) {
    float s = 0.f;
    ((s = fma4<EBASE + 4*(int)Qs>(ld4(lds, RBASE + 4*(int)Qs), e, s)), ...);
    return s;
}
template <int T, int A, int B, size_t... IIs>   // off-diagonal 13x13 block
__device__ __forceinline__ void block_off(const float* lds, const float (&e)[EPAD],
                                          float (&acc)[4], std::index_sequence<IIs...>) {
    ((acc[IIs & 3] = fmaf(e[A*TILE + (int)IIs],
         row_q<off_base(T) + (int)IIs*OFF_ROW, B*TILE>(lds, e, std::make_index_sequence<4>{}),
         acc[IIs & 3])), ...);
}
template <int A, size_t... IIs>                 // diagonal triangular block
__device__ __forceinline__ void block_diag(const float* lds, const float (&e)[EPAD],
                                           float (&acc)[4], std::index_sequence<IIs...>) {
    ((acc[IIs & 3] = fmaf(e[A*TILE + (int)IIs],
         row_q<diag_base(A) + diag_rowstart((int)IIs), A*TILE + (int)IIs + 1>(
             lds, e, std::make_index_sequence<(size_t)(ceil4(TILE-1-(int)IIs)/4)>{}),
         acc[IIs & 3])), ...);
}
template <size_t... Fs>
__device__ __forceinline__ void gather_all(const int* __restrict__ rowIdx,
                                           const float* __restrict__ emb,
                                           int d, float (&e)[EPAD],
                                           std::index_sequence<Fs...>) {
    int idx[FIELD];
    ((idx[Fs] = rowIdx[Fs]), ...);                        // wave-uniform -> s_load batches
    ((e[Fs] = emb[(size_t)idx[Fs] * DIM + d]), ...);      // 39 gathers, 1 line/instr
}

// ONE ROW PER WAVE: lane = q*16 + d; the 4 lane-quarters are redundant dim
// replicas, so every gather instruction touches a single 64B row (1 transaction)
// and 8192 waves (vs 2048) give 2-4x the in-flight gathers for latency hiding.
__global__ __launch_bounds__(256, 4) void fwfm_kernel(
    const int*   __restrict__ inputs,   // [BATCH][FIELD]
    const float* __restrict__ emb,      // [1M][DIM]
    const float* __restrict__ fw,       // [741]
    const float* __restrict__ lw,       // [1M]
    const float* __restrict__ bias,     // [1]
    float*       __restrict__ out)      // [BATCH]
{
    __shared__ __align__(16) float wlds[WTOT];

    const int tid  = threadIdx.x;
    const int lane = tid & 63;
    const int wave = tid >> 6;
    const int d    = lane & 15;                 // dim owned by this lane
    const int row  = blockIdx.x * 4 + wave;     // 2048 blocks * 4 waves = 8192 rows

    const int* rowIdx = inputs + row * FIELD;

    // ---- issue the long-latency gathers first ----
    float e[EPAD];
    gather_all(rowIdx, emb, d, e, std::make_index_sequence<FIELD>{});
    e[39] = 0.f; e[40] = 0.f; e[41] = 0.f;

    // ---- first order: 39 fields split across the 16 dim-lanes (replicated x4) ----
    float fo = lw[rowIdx[d]] + lw[rowIdx[d + 16]];
    if (d < 7) fo += lw[rowIdx[d + 32]];

    // ---- stage packed weights into LDS (overlaps gather latency) ----
    for (int s = tid; s < WTOT; s += 256) {
        int m = g_map.v[s];
        wlds[s] = (m >= 0) ? fw[m] : 0.f;
    }
    __syncthreads();

    // ---- second order over 6 tile blocks (all lanes: full pair list for dim d) ----
    float acc[4] = {0.f, 0.f, 0.f, 0.f};
    const auto seqT = std::make_index_sequence<TILE>{};
    block_off<0, 0, 1>(wlds, e, acc, seqT);
    block_off<1, 0, 2>(wlds, e, acc, seqT);
    block_off<2, 1, 2>(wlds, e, acc, seqT);
    block_diag<0>(wlds, e, acc, seqT);
    block_diag<1>(wlds, e, acc, seqT);
    block_diag<2>(wlds, e, acc, seqT);
    float so = (acc[0] + acc[1]) + (acc[2] + acc[3]);

    // ---- reduce the 16 dims (within each 16-lane quarter; quarters identical) ----
    float tot = fo + so;
    tot += __shfl_xor(tot, 1, 64);
    tot += __shfl_xor(tot, 2, 64);
    tot += __shfl_xor(tot, 4, 64);
    tot += __shfl_xor(tot, 8, 64);

    if (lane == 0) out[row] = tot + bias[0];
}

extern "C" void kernel_launch(void* const* d_in, const int* in_sizes, int n_in,
                              void* d_out, int out_size, void* d_ws, size_t ws_size,
                              hipStream_t stream) {
    const int*   inputs = (const int*)  d_in[0];
    const float* emb    = (const float*)d_in[1];
    const float* fw     = (const float*)d_in[2];
    const float* lw     = (const float*)d_in[3];
    const float* bias   = (const float*)d_in[4];
    float*       out    = (float*)      d_out;

    dim3 grid(BATCH / 4);   // 2048 blocks * 4 waves * 1 row/wave = 8192 rows
    fwfm_kernel<<<grid, 256, 0, stream>>>(inputs, emb, fw, lw, bias, out);
}

// Round 7
// 110.527 us; speedup vs baseline: 1.1148x; 1.1148x over previous
//
#include <hip/hip_runtime.h>
#include <utility>

#define FIELD 39
#define TILE  13      // 3 tiles of 13
#define DIM   16
#define BATCH 8192
#define EPAD  42      // 39 real + 3 zero pad
#define RPB   16      // rows per block
#define ROWF  (FIELD * DIM)          // 624 floats per row staged in LDS
#define CHUNKS (RPB * FIELD * 4)     // 2496 float4 chunks per block

// ---- compile-time packed weight layout: every row 16B-aligned ----
constexpr int widx(int i, int j) { return i*(FIELD-1) - i*(i-1)/2 + (j-i-1); }
constexpr int ceil4(int x) { return (x+3) & ~3; }
constexpr int OFF_ROW  = 16;
constexpr int OFF_TILE = TILE * OFF_ROW;     // 208
constexpr int diag_rowstart(int II) {
    int s = 0; for (int m = 0; m < II; ++m) s += ceil4(TILE-1-m); return s;
}
constexpr int DIAG_TILE = diag_rowstart(TILE);          // 96
constexpr int off_base(int t) { return t * OFF_TILE; }
constexpr int diag_base(int A) { return 3*OFF_TILE + A*DIAG_TILE; }
constexpr int WTOT = 3*OFF_TILE + 3*DIAG_TILE;          // 912 floats

struct WMap { int v[WTOT]; };
constexpr WMap make_map() {
    WMap m{};
    for (int i = 0; i < WTOT; ++i) m.v[i] = -1;
    const int AB[3][2] = {{0,1},{0,2},{1,2}};
    for (int t = 0; t < 3; ++t)
        for (int II = 0; II < TILE; ++II)
            for (int c = 0; c < TILE; ++c)
                m.v[off_base(t) + II*OFF_ROW + c] = widx(AB[t][0]*TILE+II, AB[t][1]*TILE+c);
    for (int A = 0; A < 3; ++A)
        for (int II = 0; II < TILE-1; ++II)
            for (int k = 0; k < TILE-1-II; ++k)
                m.v[diag_base(A) + diag_rowstart(II) + k] = widx(A*TILE+II, A*TILE+II+1+k);
    return m;
}
__device__ constexpr WMap g_map = make_map();

// ---- pair-loop machinery (all indices literal after instantiation) ----
__device__ __forceinline__ float4 ld4(const float* lds, int ofs) {
    return *reinterpret_cast<const float4*>(lds + ofs);   // ds_read_b128 imm offset
}
template <int EB>
__device__ __forceinline__ float fma4(float4 w, const float (&e)[EPAD], float s) {
    s = fmaf(w.x, e[EB+0], s); s = fmaf(w.y, e[EB+1], s);
    s = fmaf(w.z, e[EB+2], s); s = fmaf(w.w, e[EB+3], s);
    return s;
}
template <int RBASE, int EBASE, size_t... Qs>
__device__ __forceinline__ float row_q(const float* lds, const float (&e)[EPAD],
                                       std::index_sequence<Qs...>) {
    float s = 0.f;
    ((s = fma4<EBASE + 4*(int)Qs>(ld4(lds, RBASE + 4*(int)Qs), e, s)), ...);
    return s;
}
template <int T, int A, int B, size_t... IIs>
__device__ __forceinline__ void block_off(const float* lds, const float (&e)[EPAD],
                                          float (&acc)[4], std::index_sequence<IIs...>) {
    ((acc[IIs & 3] = fmaf(e[A*TILE + (int)IIs],
         row_q<off_base(T) + (int)IIs*OFF_ROW, B*TILE>(lds, e, std::make_index_sequence<4>{}),
         acc[IIs & 3])), ...);
}
template <int A, size_t... IIs>
__device__ __forceinline__ void block_diag(const float* lds, const float (&e)[EPAD],
                                           float (&acc)[4], std::index_sequence<IIs...>) {
    ((acc[IIs & 3] = fmaf(e[A*TILE + (int)IIs],
         row_q<diag_base(A) + diag_rowstart((int)IIs), A*TILE + (int)IIs + 1>(
             lds, e, std::make_index_sequence<(size_t)(ceil4(TILE-1-(int)IIs)/4)>{}),
         acc[IIs & 3])), ...);
}
template <size_t... Fs>
__device__ __forceinline__ void eread(const float* __restrict__ elds_row, int d,
                                      float (&e)[EPAD], std::index_sequence<Fs...>) {
    ((e[Fs] = elds_row[(int)Fs * DIM + d]), ...);   // ds_read, 2-way bank alias = free
}

// Phase 1: 256 threads cooperatively stage 16 rows x 39 fields x 64B into LDS
// (chunk c -> LDS float offset c*4, source row ilds[c>>2], quad c&3). 10 unrolled
// float4 loads/thread => ~1280 lines in flight per CU: gather MLP no longer
// depends on register allocation. Phase 2: R5's fold-expression pair loop.
__global__ __launch_bounds__(256, 2) void fwfm_kernel(
    const int*   __restrict__ inputs,   // [BATCH][FIELD]
    const float* __restrict__ emb,      // [1M][DIM]
    const float* __restrict__ fw,       // [741]
    const float* __restrict__ lw,       // [1M]
    const float* __restrict__ bias,     // [1]
    float*       __restrict__ out)      // [BATCH]
{
    __shared__ __align__(16) float elds[RPB * ROWF];   // 39936 B
    __shared__ int   ilds[RPB * FIELD];                // 2496 B
    __shared__ __align__(16) float wlds[WTOT];         // 3648 B

    const int tid = threadIdx.x;

    // ---- stage this block's 624 indices (contiguous, coalesced) ----
    const int* ibase = inputs + blockIdx.x * (RPB * FIELD);
    for (int s = tid; s < RPB * FIELD; s += 256) ilds[s] = ibase[s];
    // ---- stage packed pair weights ----
    for (int s = tid; s < WTOT; s += 256) {
        int m = g_map.v[s];
        wlds[s] = (m >= 0) ? fw[m] : 0.f;
    }
    __syncthreads();

    // ---- cooperative gather: all loads issued back-to-back (40 VGPRs live) ----
    float4 v[10];
    #pragma unroll
    for (int k = 0; k < 10; ++k) {
        int c = tid + (k << 8);
        c = (c < CHUNKS) ? c : 0;                       // only k==9, tid>=192 clamps
        v[k] = *(const float4*)(emb + (size_t)ilds[c >> 2] * DIM + ((c & 3) << 2));
    }
    #pragma unroll
    for (int k = 0; k < 10; ++k) {
        int c = tid + (k << 8);
        if (c < CHUNKS) *(float4*)(elds + (c << 2)) = v[k];
    }
    __syncthreads();

    // ---- compute phase: 4 rows per wave, lane = rloc*16 + d ----
    const int lane = tid & 63;
    const int wave = tid >> 6;
    const int d    = lane & 15;
    const int rloc = lane >> 4;
    const int row  = wave * 4 + rloc;            // 0..15 within block

    // first-order gathers issued early (overlap the pair loop)
    const int* ri = ilds + row * FIELD;
    float l0 = lw[ri[d]], l1 = lw[ri[d + 16]];
    float l2 = (d < 7) ? lw[ri[d + 32]] : 0.f;

    float e[EPAD];
    eread(elds + row * ROWF, d, e, std::make_index_sequence<FIELD>{});
    e[39] = 0.f; e[40] = 0.f; e[41] = 0.f;

    float acc[4] = {0.f, 0.f, 0.f, 0.f};
    const auto seqT = std::make_index_sequence<TILE>{};
    block_off<0, 0, 1>(wlds, e, acc, seqT);
    block_off<1, 0, 2>(wlds, e, acc, seqT);
    block_off<2, 1, 2>(wlds, e, acc, seqT);
    block_diag<0>(wlds, e, acc, seqT);
    block_diag<1>(wlds, e, acc, seqT);
    block_diag<2>(wlds, e, acc, seqT);
    float so = (acc[0] + acc[1]) + (acc[2] + acc[3]);

    // ---- reduce the 16 dim-lanes of this row ----
    float tot = so + (l0 + l1 + l2);
    tot += __shfl_xor(tot, 1, 64);
    tot += __shfl_xor(tot, 2, 64);
    tot += __shfl_xor(tot, 4, 64);
    tot += __shfl_xor(tot, 8, 64);

    if (d == 0) out[blockIdx.x * RPB + row] = tot + bias[0];
}

extern "C" void kernel_launch(void* const* d_in, const int* in_sizes, int n_in,
                              void* d_out, int out_size, void* d_ws, size_t ws_size,
                              hipStream_t stream) {
    const int*   inputs = (const int*)  d_in[0];
    const float* emb    = (const float*)d_in[1];
    const float* fw     = (const float*)d_in[2];
    const float* lw     = (const float*)d_in[3];
    const float* bias   = (const float*)d_in[4];
    float*       out    = (float*)      d_out;

    dim3 grid(BATCH / RPB);   // 512 blocks * 16 rows = 8192 rows
    fwfm_kernel<<<grid, 256, 0, stream>>>(inputs, emb, fw, lw, bias, out);
}